// Round 8
// baseline (603.455 us; speedup 1.0000x reference)
//
#include <hip/hip_runtime.h>

// ---------- types ----------
typedef short s16x8 __attribute__((ext_vector_type(8)));   // 8 bf16 (4 VGPRs)
typedef float f32x4 __attribute__((ext_vector_type(4)));

static __device__ __forceinline__ unsigned short f2bf(float f) {
  unsigned u = __builtin_bit_cast(unsigned, f);
  return (unsigned short)((u + 0x7FFFu + ((u >> 16) & 1u)) >> 16);   // RNE; finite
}

// async global->LDS, 16B per lane; LDS dst must be wave-uniform base (lane*16 implicit)
#define GLL16(G, L) __builtin_amdgcn_global_load_lds( \
    (const __attribute__((address_space(1))) void*)(G), \
    (__attribute__((address_space(3))) void*)(L), 16, 0, 0)

#define KD 512
// B=16, T=512, C=19, E=512, H=8, HD=64; groups = 8192, rows = 155648.
// Fragment layout everywhere: frag (tile16, ktile32) = 1 KB: lane lf = (row&15) + 16*jc
// holds 16 B (8 bf16) at [row][ktile*32 + jc*8]. MFMA A/B reads are lane*16-linear.

// ---------- kernel: eeg fp32 -> bf16 fragment layout ----------
__global__ __launch_bounds__(256)
void k_conva(const float* __restrict__ src, unsigned short* __restrict__ dst) {
  int gid = blockIdx.x * 256 + threadIdx.x;
  int mt = gid >> 10, slot = gid & 1023;
  int kt = slot >> 6, lf = slot & 63;
  int row = mt * 16 + (lf & 15);
  int jc  = lf >> 4;
  const float* p = src + (long)row * KD + kt * 32 + jc * 8;
  float4 v0 = *(const float4*)p;
  float4 v1 = *(const float4*)(p + 4);
  s16x8 o;
  o[0]=(short)f2bf(v0.x); o[1]=(short)f2bf(v0.y); o[2]=(short)f2bf(v0.z); o[3]=(short)f2bf(v0.w);
  o[4]=(short)f2bf(v1.x); o[5]=(short)f2bf(v1.y); o[6]=(short)f2bf(v1.z); o[7]=(short)f2bf(v1.w);
  *(s16x8*)(dst + ((long)mt * 16 + kt) * 512 + (long)lf * 8) = o;
}

// ---------- kernel: weights fp32 -> bf16 fragment layout (rows 0..511 wq, 512..1023 wk) ----------
__global__ __launch_bounds__(256)
void k_convw(const float* __restrict__ wq, const float* __restrict__ wk,
             unsigned short* __restrict__ Wf) {
  int gid = blockIdx.x * 256 + threadIdx.x;   // 65536 threads
  int nt = gid >> 10, slot = gid & 1023;
  int kt = slot >> 6, lf = slot & 63;
  int f  = nt * 16 + (lf & 15);
  int jc = lf >> 4;
  const float* p = ((f < 512) ? (wq + (long)f * KD) : (wk + (long)(f - 512) * KD)) + kt * 32 + jc * 8;
  float4 v0 = *(const float4*)p;
  float4 v1 = *(const float4*)(p + 4);
  s16x8 o;
  o[0]=(short)f2bf(v0.x); o[1]=(short)f2bf(v0.y); o[2]=(short)f2bf(v0.z); o[3]=(short)f2bf(v0.w);
  o[4]=(short)f2bf(v1.x); o[5]=(short)f2bf(v1.y); o[6]=(short)f2bf(v1.z); o[7]=(short)f2bf(v1.w);
  *(s16x8*)(Wf + ((long)nt * 16 + kt) * 512 + (long)lf * 8) = o;
}

// ---------- kernel: QK = A @ [Wq^T | Wk^T] + bias (m97 structure + XCD swizzle) ----------
__global__ __launch_bounds__(256, 5)
void k_gemm(const unsigned short* __restrict__ Af, const unsigned short* __restrict__ Wf,
            const float* __restrict__ bq, const float* __restrict__ bk,
            unsigned short* __restrict__ QK) {
  __shared__ unsigned short Abuf[16 * 512];   // 16 frags: slot = ksub*8 + msub
  __shared__ unsigned short Bbuf[16 * 512];   // 16 frags: slot = ksub*8 + nsub

  const int tid  = threadIdx.x;
  const int lane = tid & 63;
  const int wid  = tid >> 6;      // 0..3
  const int wr   = wid >> 1, wc = wid & 1;
  const int rlo  = lane & 15, rhi = lane >> 4;

  // XCD-chunked swizzle (assumes HW xcd = blockIdx % 8; nwg % 8 == 0 -> bijective):
  // each XCD gets a contiguous run of logical tiles, so the 8 bn-blocks sharing an
  // A panel are temporally adjacent on ONE XCD -> panel fetched into that L2 once.
  const int cpx = gridDim.x >> 3;
  const int L   = (blockIdx.x & 7) * cpx + (blockIdx.x >> 3);
  const int mb  = L >> 3;
  const int bn  = L & 7;

#define STAGE(KK) do { \
    if (wid < 2) { \
      _Pragma("unroll") for (int s = 0; s < 8; ++s) { \
        int slot = wid * 8 + s; \
        const unsigned short* g = Af + ((long)(mb * 8 + (slot & 7)) * 16 + (KK) * 2 + (slot >> 3)) * 512 + lane * 8; \
        GLL16(g, &Abuf[slot * 512]); \
      } \
    } else { \
      _Pragma("unroll") for (int s = 0; s < 8; ++s) { \
        int slot = (wid - 2) * 8 + s; \
        const unsigned short* g = Wf + ((long)(bn * 8 + (slot & 7)) * 16 + (KK) * 2 + (slot >> 3)) * 512 + lane * 8; \
        GLL16(g, &Bbuf[slot * 512]); \
      } \
    } \
  } while (0)

  f32x4 acc[4][4] = {};
  STAGE(0);
  __syncthreads();   // drains vmcnt(0): buffer ready

#pragma unroll 1
  for (int kk = 0; kk < 8; ++kk) {
#pragma unroll
    for (int ksub = 0; ksub < 2; ++ksub) {
      s16x8 af[4], bfr[4];
#pragma unroll
      for (int m = 0; m < 4; ++m)
        af[m] = *(const s16x8*)&Abuf[(ksub * 8 + wr * 4 + m) * 512 + lane * 8];
#pragma unroll
      for (int n = 0; n < 4; ++n)
        bfr[n] = *(const s16x8*)&Bbuf[(ksub * 8 + wc * 4 + n) * 512 + lane * 8];
#pragma unroll
      for (int m = 0; m < 4; ++m)
#pragma unroll
        for (int n = 0; n < 4; ++n)
          acc[m][n] = __builtin_amdgcn_mfma_f32_16x16x32_bf16(af[m], bfr[n], acc[m][n], 0, 0, 0);
    }
    if (kk < 7) {
      __syncthreads();     // all reads of buffer done
      STAGE(kk + 1);
      __syncthreads();     // vmcnt(0) drain: next buffer ready
    }
  }
#undef STAGE

  // ---- epilogue: bias + bf16 store ----
#pragma unroll
  for (int n = 0; n < 4; ++n) {
    int colg = bn * 128 + wc * 64 + n * 16 + rlo;
    float bias = (colg < 512) ? bq[colg] : bk[colg - 512];
#pragma unroll
    for (int m = 0; m < 4; ++m) {
      long rl = (long)mb * 128 + wr * 64 + m * 16 + (rhi << 2);
#pragma unroll
      for (int j = 0; j < 4; ++j)
        QK[(rl + j) * 1024 + colg] = f2bf(acc[m][n][j] + bias);
    }
  }
}

// ---------- kernel: per-group attention -> atomic strength accumulation ----------
__global__ __launch_bounds__(256, 3)
void k_attn(const unsigned short* __restrict__ QK, float* __restrict__ acc, int g0) {
  __shared__ unsigned short Qs[19][1032];
  __shared__ float Sc[8][19][20];
  __shared__ float red[256];

  const int tid  = threadIdx.x;
  const int lane = tid & 63;
  const int wid  = tid >> 6;
  const long gl  = blockIdx.x;

  const unsigned short* src = QK + gl * 19 * 1024;
  for (int c = tid; c < 2432; c += 256) {
    int row = c >> 7, c8 = (c & 127) << 3;
    *(s16x8*)&Qs[row][c8] = *(const s16x8*)(src + row * 1024 + c8);
  }
  __syncthreads();

  const int rlo = lane & 15, rhi = lane >> 4;
  const s16x8 z8 = {};
#pragma unroll
  for (int hh = 0; hh < 2; ++hh) {
    const int h = wid * 2 + hh;
    f32x4 s[2][2] = {};
#pragma unroll
    for (int ks = 0; ks < 2; ++ks) {
      s16x8 qa[2], kb[2];
#pragma unroll
      for (int mi = 0; mi < 2; ++mi) {
        int r = mi * 16 + rlo;
        qa[mi] = (r < 19) ? *(const s16x8*)&Qs[r][h * 64 + ks * 32 + rhi * 8] : z8;
        kb[mi] = (r < 19) ? *(const s16x8*)&Qs[r][512 + h * 64 + ks * 32 + rhi * 8] : z8;
      }
#pragma unroll
      for (int mi = 0; mi < 2; ++mi)
#pragma unroll
        for (int nj = 0; nj < 2; ++nj)
          s[mi][nj] = __builtin_amdgcn_mfma_f32_16x16x32_bf16(qa[mi], kb[nj], s[mi][nj], 0, 0, 0);
    }
#pragma unroll
    for (int mi = 0; mi < 2; ++mi)
#pragma unroll
      for (int nj = 0; nj < 2; ++nj)
#pragma unroll
        for (int j = 0; j < 4; ++j) {
          int r = mi * 16 + rhi * 4 + j, c = nj * 16 + rlo;
          if (r < 19 && c < 19) Sc[h][r][c] = s[mi][nj][j] * 0.125f;
        }
  }
  __syncthreads();

  float p = 0.f;
  if (tid < 152) {
    int h = tid / 19, i = tid - h * 19;
    float sv[19];
    float mx = -1e30f;
#pragma unroll
    for (int j = 0; j < 19; ++j) { sv[j] = Sc[h][i][j]; mx = fmaxf(mx, sv[j]); }
    float sum = 0.f, up = 0.f;
#pragma unroll
    for (int j = 0; j < 19; ++j) {
      float e = __expf(sv[j] - mx);
      sum += e;
      if (j > i) up += e;
    }
    p = up / sum;
  }
  red[tid] = p;
  __syncthreads();
  for (int off = 128; off > 0; off >>= 1) {
    if (tid < off) red[tid] += red[tid + off];
    __syncthreads();
  }
  if (tid == 0) {
    int b = (g0 + (int)blockIdx.x) >> 9;
    atomicAdd(&acc[b], red[0]);
  }
}

// ---------- kernel: finalize out[b] = clip(acc[b] / (8*171*512), 0, 1) ----------
__global__ void k_fin(const float* __restrict__ acc, float* __restrict__ out) {
  int t = threadIdx.x;
  if (t < 16) {
    float v = acc[t] * (1.0f / 700416.0f);
    out[t] = fminf(1.0f, fmaxf(0.0f, v));
  }
}

// ---------- host ----------
extern "C" void kernel_launch(void* const* d_in, const int* in_sizes, int n_in,
                              void* d_out, int out_size, void* d_ws, size_t ws_size,
                              hipStream_t stream) {
  const float* eeg = (const float*)d_in[0];
  const float* wq  = (const float*)d_in[1];
  const float* wk  = (const float*)d_in[2];
  const float* bq  = (const float*)d_in[3];
  const float* bk  = (const float*)d_in[4];
  float* out = (float*)d_out;

  char* ws = (char*)d_ws;
  unsigned short* Wf = (unsigned short*)ws;          // 1 MiB frag-layout weights
  float* acc = (float*)(ws + (1 << 20));             // 64 B accumulators
  long off = (1 << 20) + 256;

  // per-group: Af 19456 B, QK 38912 B. Single chunk when ws permits (R7 lesson:
  // chunking on one stream only adds ramp/drain tails, no traffic savings).
  long avail = (long)ws_size - off;
  long G = avail / 58368;
  G = (G / 128) * 128;
  if (G > 8192) G = 8192;
  if (G < 128) G = 128;
  unsigned short* Afb = (unsigned short*)(ws + off);
  unsigned short* QKb = (unsigned short*)(ws + off + G * 19456L);

  hipMemsetAsync(acc, 0, 64, stream);
  k_convw<<<256, 256, 0, stream>>>(wq, wk, Wf);

  for (int g0 = 0; g0 < 8192; g0 += (int)G) {
    int cg = 8192 - g0; if (cg > (int)G) cg = (int)G;
    int rows   = cg * 19;            // cg multiple of 128 -> rows multiple of 2432
    int mtiles = rows / 16;
    k_conva<<<mtiles * 4, 256, 0, stream>>>(eeg + (long)g0 * 19 * KD, Afb);
    k_gemm<<<(rows / 128) * 8, 256, 0, stream>>>(Afb, Wf, bq, bk, QKb);
    k_attn<<<cg, 256, 0, stream>>>(QKb, acc, g0);
  }
  k_fin<<<1, 64, 0, stream>>>(acc, out);
}

// Round 9
// 442.489 us; speedup vs baseline: 1.3638x; 1.3638x over previous
//
#include <hip/hip_runtime.h>

// ---------- types ----------
typedef short s16x8 __attribute__((ext_vector_type(8)));   // 8 bf16 (4 VGPRs)
typedef float f32x4 __attribute__((ext_vector_type(4)));

static __device__ __forceinline__ unsigned short f2bf(float f) {
  unsigned u = __builtin_bit_cast(unsigned, f);
  return (unsigned short)((u + 0x7FFFu + ((u >> 16) & 1u)) >> 16);   // RNE; finite
}

// async global->LDS, 16B per lane; LDS dst must be wave-uniform base (lane*16 implicit)
#define GLL16(G, L) __builtin_amdgcn_global_load_lds( \
    (const __attribute__((address_space(1))) void*)(G), \
    (__attribute__((address_space(3))) void*)(L), 16, 0, 0)

#define KD 512
// B=16, T=512, C=19, E=512, H=8, HD=64; groups = 8192, rows = 155648.
// Fragment layout everywhere: frag (tile16, ktile32) = 1 KB: lane lf = (row&15) + 16*jc
// holds 16 B (8 bf16) at [row][ktile*32 + jc*8]. MFMA A/B reads are lane*16-linear.

// ---------- kernel: eeg fp32 -> bf16 fragment layout ----------
__global__ __launch_bounds__(256)
void k_conva(const float* __restrict__ src, unsigned short* __restrict__ dst) {
  int gid = blockIdx.x * 256 + threadIdx.x;
  int mt = gid >> 10, slot = gid & 1023;
  int kt = slot >> 6, lf = slot & 63;
  int row = mt * 16 + (lf & 15);
  int jc  = lf >> 4;
  const float* p = src + (long)row * KD + kt * 32 + jc * 8;
  float4 v0 = *(const float4*)p;
  float4 v1 = *(const float4*)(p + 4);
  s16x8 o;
  o[0]=(short)f2bf(v0.x); o[1]=(short)f2bf(v0.y); o[2]=(short)f2bf(v0.z); o[3]=(short)f2bf(v0.w);
  o[4]=(short)f2bf(v1.x); o[5]=(short)f2bf(v1.y); o[6]=(short)f2bf(v1.z); o[7]=(short)f2bf(v1.w);
  *(s16x8*)(dst + ((long)mt * 16 + kt) * 512 + (long)lf * 8) = o;
}

// ---------- kernel: weights fp32 -> bf16 fragment layout (rows 0..511 wq, 512..1023 wk) ----------
__global__ __launch_bounds__(256)
void k_convw(const float* __restrict__ wq, const float* __restrict__ wk,
             unsigned short* __restrict__ Wf) {
  int gid = blockIdx.x * 256 + threadIdx.x;   // 65536 threads
  int nt = gid >> 10, slot = gid & 1023;
  int kt = slot >> 6, lf = slot & 63;
  int f  = nt * 16 + (lf & 15);
  int jc = lf >> 4;
  const float* p = ((f < 512) ? (wq + (long)f * KD) : (wk + (long)(f - 512) * KD)) + kt * 32 + jc * 8;
  float4 v0 = *(const float4*)p;
  float4 v1 = *(const float4*)(p + 4);
  s16x8 o;
  o[0]=(short)f2bf(v0.x); o[1]=(short)f2bf(v0.y); o[2]=(short)f2bf(v0.z); o[3]=(short)f2bf(v0.w);
  o[4]=(short)f2bf(v1.x); o[5]=(short)f2bf(v1.y); o[6]=(short)f2bf(v1.z); o[7]=(short)f2bf(v1.w);
  *(s16x8*)(Wf + ((long)nt * 16 + kt) * 512 + (long)lf * 8) = o;
}

// ---------- kernel: QK = A @ [Wq^T | Wk^T] + bias (m97 structure + XCD swizzle) ----------
// launch_bounds(256,4): 4 waves/EU -> 128 unified regs/wave; acc = 64 AGPR + ~60 VGPR
// fits with zero spill (R8's occ=5 capped at ~102 regs -> accumulator spill, +130 MB
// scratch writes, +145 us. Occupancy must not be bought with registers in use.)
__global__ __launch_bounds__(256, 4)
void k_gemm(const unsigned short* __restrict__ Af, const unsigned short* __restrict__ Wf,
            const float* __restrict__ bq, const float* __restrict__ bk,
            unsigned short* __restrict__ QK) {
  __shared__ unsigned short Abuf[16 * 512];   // 16 frags: slot = ksub*8 + msub
  __shared__ unsigned short Bbuf[16 * 512];   // 16 frags: slot = ksub*8 + nsub

  const int tid  = threadIdx.x;
  const int lane = tid & 63;
  const int wid  = tid >> 6;      // 0..3
  const int wr   = wid >> 1, wc = wid & 1;
  const int rlo  = lane & 15, rhi = lane >> 4;

  // XCD-chunked swizzle (HW xcd = blockIdx % 8; nwg % 8 == 0 -> bijective):
  // each XCD gets a contiguous run of logical tiles, so the 8 bn-blocks sharing an
  // A panel are temporally adjacent on ONE XCD -> panel fetched into that L2 once.
  // (R8 verified: FETCH 623 -> 147 MB.)
  const int cpx = gridDim.x >> 3;
  const int L   = (blockIdx.x & 7) * cpx + (blockIdx.x >> 3);
  const int mb  = L >> 3;
  const int bn  = L & 7;

#define STAGE(KK) do { \
    if (wid < 2) { \
      _Pragma("unroll") for (int s = 0; s < 8; ++s) { \
        int slot = wid * 8 + s; \
        const unsigned short* g = Af + ((long)(mb * 8 + (slot & 7)) * 16 + (KK) * 2 + (slot >> 3)) * 512 + lane * 8; \
        GLL16(g, &Abuf[slot * 512]); \
      } \
    } else { \
      _Pragma("unroll") for (int s = 0; s < 8; ++s) { \
        int slot = (wid - 2) * 8 + s; \
        const unsigned short* g = Wf + ((long)(bn * 8 + (slot & 7)) * 16 + (KK) * 2 + (slot >> 3)) * 512 + lane * 8; \
        GLL16(g, &Bbuf[slot * 512]); \
      } \
    } \
  } while (0)

  f32x4 acc[4][4] = {};
  STAGE(0);
  __syncthreads();   // drains vmcnt(0): buffer ready

#pragma unroll 1
  for (int kk = 0; kk < 8; ++kk) {
#pragma unroll
    for (int ksub = 0; ksub < 2; ++ksub) {
      s16x8 af[4], bfr[4];
#pragma unroll
      for (int m = 0; m < 4; ++m)
        af[m] = *(const s16x8*)&Abuf[(ksub * 8 + wr * 4 + m) * 512 + lane * 8];
#pragma unroll
      for (int n = 0; n < 4; ++n)
        bfr[n] = *(const s16x8*)&Bbuf[(ksub * 8 + wc * 4 + n) * 512 + lane * 8];
#pragma unroll
      for (int m = 0; m < 4; ++m)
#pragma unroll
        for (int n = 0; n < 4; ++n)
          acc[m][n] = __builtin_amdgcn_mfma_f32_16x16x32_bf16(af[m], bfr[n], acc[m][n], 0, 0, 0);
    }
    if (kk < 7) {
      __syncthreads();     // all reads of buffer done
      STAGE(kk + 1);
      __syncthreads();     // vmcnt(0) drain: next buffer ready
    }
  }
#undef STAGE

  // ---- epilogue: bias + bf16 store ----
#pragma unroll
  for (int n = 0; n < 4; ++n) {
    int colg = bn * 128 + wc * 64 + n * 16 + rlo;
    float bias = (colg < 512) ? bq[colg] : bk[colg - 512];
#pragma unroll
    for (int m = 0; m < 4; ++m) {
      long rl = (long)mb * 128 + wr * 64 + m * 16 + (rhi << 2);
#pragma unroll
      for (int j = 0; j < 4; ++j)
        QK[(rl + j) * 1024 + colg] = f2bf(acc[m][n][j] + bias);
    }
  }
}

// ---------- kernel: per-group attention -> atomic strength accumulation ----------
__global__ __launch_bounds__(256, 3)
void k_attn(const unsigned short* __restrict__ QK, float* __restrict__ acc, int g0) {
  __shared__ unsigned short Qs[19][1032];
  __shared__ float Sc[8][19][20];
  __shared__ float red[256];

  const int tid  = threadIdx.x;
  const int lane = tid & 63;
  const int wid  = tid >> 6;
  const long gl  = blockIdx.x;

  const unsigned short* src = QK + gl * 19 * 1024;
  for (int c = tid; c < 2432; c += 256) {
    int row = c >> 7, c8 = (c & 127) << 3;
    *(s16x8*)&Qs[row][c8] = *(const s16x8*)(src + row * 1024 + c8);
  }
  __syncthreads();

  const int rlo = lane & 15, rhi = lane >> 4;
  const s16x8 z8 = {};
#pragma unroll
  for (int hh = 0; hh < 2; ++hh) {
    const int h = wid * 2 + hh;
    f32x4 s[2][2] = {};
#pragma unroll
    for (int ks = 0; ks < 2; ++ks) {
      s16x8 qa[2], kb[2];
#pragma unroll
      for (int mi = 0; mi < 2; ++mi) {
        int r = mi * 16 + rlo;
        qa[mi] = (r < 19) ? *(const s16x8*)&Qs[r][h * 64 + ks * 32 + rhi * 8] : z8;
        kb[mi] = (r < 19) ? *(const s16x8*)&Qs[r][512 + h * 64 + ks * 32 + rhi * 8] : z8;
      }
#pragma unroll
      for (int mi = 0; mi < 2; ++mi)
#pragma unroll
        for (int nj = 0; nj < 2; ++nj)
          s[mi][nj] = __builtin_amdgcn_mfma_f32_16x16x32_bf16(qa[mi], kb[nj], s[mi][nj], 0, 0, 0);
    }
#pragma unroll
    for (int mi = 0; mi < 2; ++mi)
#pragma unroll
      for (int nj = 0; nj < 2; ++nj)
#pragma unroll
        for (int j = 0; j < 4; ++j) {
          int r = mi * 16 + rhi * 4 + j, c = nj * 16 + rlo;
          if (r < 19 && c < 19) Sc[h][r][c] = s[mi][nj][j] * 0.125f;
        }
  }
  __syncthreads();

  float p = 0.f;
  if (tid < 152) {
    int h = tid / 19, i = tid - h * 19;
    float sv[19];
    float mx = -1e30f;
#pragma unroll
    for (int j = 0; j < 19; ++j) { sv[j] = Sc[h][i][j]; mx = fmaxf(mx, sv[j]); }
    float sum = 0.f, up = 0.f;
#pragma unroll
    for (int j = 0; j < 19; ++j) {
      float e = __expf(sv[j] - mx);
      sum += e;
      if (j > i) up += e;
    }
    p = up / sum;
  }
  red[tid] = p;
  __syncthreads();
  for (int off = 128; off > 0; off >>= 1) {
    if (tid < off) red[tid] += red[tid + off];
    __syncthreads();
  }
  if (tid == 0) {
    int b = (g0 + (int)blockIdx.x) >> 9;
    atomicAdd(&acc[b], red[0]);
  }
}

// ---------- kernel: finalize out[b] = clip(acc[b] / (8*171*512), 0, 1) ----------
__global__ void k_fin(const float* __restrict__ acc, float* __restrict__ out) {
  int t = threadIdx.x;
  if (t < 16) {
    float v = acc[t] * (1.0f / 700416.0f);
    out[t] = fminf(1.0f, fmaxf(0.0f, v));
  }
}

// ---------- host ----------
extern "C" void kernel_launch(void* const* d_in, const int* in_sizes, int n_in,
                              void* d_out, int out_size, void* d_ws, size_t ws_size,
                              hipStream_t stream) {
  const float* eeg = (const float*)d_in[0];
  const float* wq  = (const float*)d_in[1];
  const float* wk  = (const float*)d_in[2];
  const float* bq  = (const float*)d_in[3];
  const float* bk  = (const float*)d_in[4];
  float* out = (float*)d_out;

  char* ws = (char*)d_ws;
  unsigned short* Wf = (unsigned short*)ws;          // 1 MiB frag-layout weights
  float* acc = (float*)(ws + (1 << 20));             // 64 B accumulators
  long off = (1 << 20) + 256;

  // per-group: Af 19456 B, QK 38912 B. Single chunk when ws permits (R7 lesson:
  // chunking on one stream only adds ramp/drain tails, no traffic savings).
  long avail = (long)ws_size - off;
  long G = avail / 58368;
  G = (G / 128) * 128;
  if (G > 8192) G = 8192;
  if (G < 128) G = 128;
  unsigned short* Afb = (unsigned short*)(ws + off);
  unsigned short* QKb = (unsigned short*)(ws + off + G * 19456L);

  hipMemsetAsync(acc, 0, 64, stream);
  k_convw<<<256, 256, 0, stream>>>(wq, wk, Wf);

  for (int g0 = 0; g0 < 8192; g0 += (int)G) {
    int cg = 8192 - g0; if (cg > (int)G) cg = (int)G;
    int rows   = cg * 19;            // cg multiple of 128 -> rows multiple of 2432
    int mtiles = rows / 16;
    k_conva<<<mtiles * 4, 256, 0, stream>>>(eeg + (long)g0 * 19 * KD, Afb);
    k_gemm<<<(rows / 128) * 8, 256, 0, stream>>>(Afb, Wf, bq, bk, QKb);
    k_attn<<<cg, 256, 0, stream>>>(QKb, acc, g0);
  }
  k_fin<<<1, 64, 0, stream>>>(acc, out);
}